// Round 7
// baseline (576.949 us; speedup 1.0000x reference)
//
#include <hip/hip_runtime.h>

// SSIM loss: pred/target [16,3,512,512] fp32, 11x11 gaussian (sigma=1.5),
// zero-padded SAME depthwise conv, output scalar 1 - mean(ssim_map).
//
// v12: v7 main kernel (best measured: 69.3us, VGPR 56, 4 blocks/CU)
// + single-kernel finish. Cross-round data shows an ADDITIVE ~85us gap
// between bench dur_us and the ssim_main dispatch time (+86.5/+85.5/+80/
// +93/+88 across v6..v11) -- launch/node overhead of the 3-op sequence,
// now bigger than the kernel itself. v12 removes the ssim_fin launch:
// last-block-done ticket (device-scope fetch_add) + agent-scope atomic
// loads of the 48 channel sums (coherent across XCDs, Guideline 16);
// the winning block computes 1 - mean and writes d_out directly.
// Register-pipeline attempts (v10/v10b/v11) are abandoned: hipcc's
// pressure-driven scheduler sinks load batches regardless of
// sched_barrier; forcing it via asm vmem broke waitcnt bookkeeping.

#define IMG 512
#define NCHAN 48
#define TW 32
#define TH 64
#define HR (TH + 10)   // 74 hsum rows per tile
#define PST 33         // padded plane row stride (float4s)
#define NBLK ((IMG / TW) * (IMG / TH) * NCHAN)  // 6144

typedef float v2f __attribute__((ext_vector_type(2)));
typedef float v4f __attribute__((ext_vector_type(4)));

constexpr double RW1 = 0.8007374029168082;
constexpr double RW2 = 0.4111122905071876;
constexpr double RW3 = 0.1353352832366127;
constexpr double RW4 = 0.0285655007845504;
constexpr double RW5 = 0.0038659201394728;
constexpr double RSUM = 1.0 + 2.0 * (RW1 + RW2 + RW3 + RW4 + RW5);
constexpr float GW[11] = {
    (float)(RW5 / RSUM), (float)(RW4 / RSUM), (float)(RW3 / RSUM),
    (float)(RW2 / RSUM), (float)(RW1 / RSUM), (float)(1.0 / RSUM),
    (float)(RW1 / RSUM), (float)(RW2 / RSUM), (float)(RW3 / RSUM),
    (float)(RW4 / RSUM), (float)(RW5 / RSUM)};

// ---- VOP3P packed fp32 (gfx90a+; hipcc never auto-emits these).
// Register-only asm: no memory ops, no waitcnt interaction.
__device__ __forceinline__ v2f pk_fma(v2f a, v2f b, v2f c) {
  v2f d;
  asm("v_pk_fma_f32 %0, %1, %2, %3" : "=v"(d) : "v"(a), "v"(b), "v"(c));
  return d;
}
__device__ __forceinline__ v2f pk_mul(v2f a, v2f b) {
  v2f d;
  asm("v_pk_mul_f32 %0, %1, %2" : "=v"(d) : "v"(a), "v"(b));
  return d;
}

// ---- Phase B building blocks: item j in [0, HR*8) = 4 hsum outputs.
template <bool CHECKED>
__device__ __forceinline__ void hload(const float* __restrict__ P,
                                      const float* __restrict__ T, int r0t,
                                      int c0, int j, v4f* vp, v4f* vt) {
  const int g = j & 7;
  const int h = j >> 3;
  const int gy = r0t - 5 + h;
  const int gx0 = c0 + g * 4 - 8;  // aligned 20-float window (mult of 4)
  if (CHECKED) {
    const bool rowok = (gy >= 0) && (gy < IMG);
    const float* __restrict__ Prow = P + (size_t)gy * IMG;
    const float* __restrict__ Trow = T + (size_t)gy * IMG;
#pragma unroll
    for (int q = 0; q < 5; ++q) {
      const int gx = gx0 + q * 4;
      vp[q] = (v4f){0.f, 0.f, 0.f, 0.f};
      vt[q] = vp[q];
      // gx is a multiple of 4 and IMG%4==0: float4 is all-in or all-out.
      if (rowok && gx >= 0 && gx < IMG) {
        vp[q] = *(const v4f*)(Prow + gx);
        vt[q] = *(const v4f*)(Trow + gx);
      }
    }
  } else {
    const float* __restrict__ Prow = P + (size_t)gy * IMG + gx0;
    const float* __restrict__ Trow = T + (size_t)gy * IMG + gx0;
#pragma unroll
    for (int q = 0; q < 5; ++q) {
      vp[q] = *(const v4f*)(Prow + q * 4);
      vt[q] = *(const v4f*)(Trow + q * 4);
    }
  }
}

__device__ __forceinline__ void hcompute(int j, const v4f* vp, const v4f* vt,
                                         float4 (*hs)[PST]) {
  const int g = j & 7;
  const int h = j >> 3;
  // (u, v) = (p+t, p-t) per pixel; only window indices 3..16 feed outputs
  // (dead lanes are DCE'd by the compiler).
  v2f uv[20], sq[20];
#pragma unroll
  for (int q = 0; q < 5; ++q) {
    const v4f p4 = vp[q], t4 = vt[q];
    uv[q * 4 + 0] = (v2f){p4.x + t4.x, p4.x - t4.x};
    uv[q * 4 + 1] = (v2f){p4.y + t4.y, p4.y - t4.y};
    uv[q * 4 + 2] = (v2f){p4.z + t4.z, p4.z - t4.z};
    uv[q * 4 + 3] = (v2f){p4.w + t4.w, p4.w - t4.w};
  }
#pragma unroll
  for (int i = 3; i <= 16; ++i) sq[i] = pk_mul(uv[i], uv[i]);
#pragma unroll
  for (int o = 0; o < 4; ++o) {
    v2f amu = (v2f){0.f, 0.f};  // (cu, cv)
    v2f asq = (v2f){0.f, 0.f};  // (cu2, cv2)
#pragma unroll
    for (int k = 0; k < 11; ++k) {
      const v2f w = (v2f){GW[k], GW[k]};
      amu = pk_fma(uv[3 + o + k], w, amu);
      asq = pk_fma(sq[3 + o + k], w, asq);
    }
    hs[h][g * 4 + o] = make_float4(amu.x, amu.y, asq.x, asq.y);
  }
}

// ---- Phase B (v7 structure): HR*8 = 592 items; tid, tid+256
// unconditional (loads hoisted so both items' b128 loads are issued
// together), tid+512 for tid<80. Compiler-scheduled.
template <bool CHECKED>
__device__ __forceinline__ void phase_b(const float* __restrict__ P,
                                        const float* __restrict__ T, int r0t,
                                        int c0, int tid, float4 (*hs)[PST]) {
  v4f ap[5], at[5], bp[5], bt[5];
  hload<CHECKED>(P, T, r0t, c0, tid, ap, at);
  hload<CHECKED>(P, T, r0t, c0, tid + 256, bp, bt);
  hcompute(tid, ap, at, hs);
  hcompute(tid + 256, bp, bt, hs);
  if (tid < HR * 8 - 512) {
    hload<CHECKED>(P, T, r0t, c0, tid + 512, ap, at);
    hcompute(tid + 512, ap, at, hs);
  }
}

__global__ __launch_bounds__(256, 4) void ssim_main(
    const float* __restrict__ pred, const float* __restrict__ tgt,
    double* __restrict__ ws, float* __restrict__ out) {
  __shared__ float4 hs[HR][PST];  // (cu, cv, cu2, cv2)
  __shared__ float wsum[4];

  const int tid = threadIdx.x;
  const int c0 = blockIdx.x * TW;
  const int r0t = blockIdx.y * TH;
  const int nc = blockIdx.z;
  const size_t base = (size_t)nc * IMG * IMG;
  const float* __restrict__ P = pred + base;
  const float* __restrict__ T = tgt + base;

  const bool interior =
      (c0 != 0) && (c0 != IMG - TW) && (r0t != 0) && (r0t != IMG - TH);
  if (interior)
    phase_b<false>(P, T, r0t, c0, tid, hs);
  else
    phase_b<true>(P, T, r0t, c0, tid, hs);
  __syncthreads();

  // ---- Phase C: vertical windowed sums, row-streaming, 8 outputs/thread
  float lsum = 0.f;
  {
    const int x = tid & (TW - 1);
    const int r0 = (tid >> 5) * 8;  // 8 strips * 8 rows = 64
    v2f amu[8], asq[8];
#pragma unroll
    for (int o = 0; o < 8; ++o) {
      amu[o] = (v2f){0.f, 0.f};
      asq[o] = (v2f){0.f, 0.f};
    }
#pragma unroll
    for (int j = 0; j < 18; ++j) {
      const float4 h4 = hs[r0 + j][x];
      const v2f hmu = (v2f){h4.x, h4.y};
      const v2f hsq = (v2f){h4.z, h4.w};
#pragma unroll
      for (int o = 0; o < 8; ++o) {
        const int k = j - o;
        if (k >= 0 && k < 11) {
          const v2f w = (v2f){GW[k], GW[k]};
          amu[o] = pk_fma(hmu, w, amu[o]);
          asq[o] = pk_fma(hsq, w, asq[o]);
        }
      }
    }
#pragma unroll
    for (int o = 0; o < 8; ++o) {
      const v2f m2 = pk_mul(amu[o], amu[o]);   // (cu^2, cv^2)
      const float cusq = m2.x, cvsq = m2.y;
      const float cu2 = asq[o].x, cv2 = asq[o].y;
      const float mu12 = 0.25f * (cusq - cvsq);       // mu1*mu2
      const float musq = 0.5f * (cusq + cvsq);        // mu1^2+mu2^2
      const float s12 = 0.25f * (cu2 - cv2);          // conv(p*t)
      const float ssq = 0.5f * (cu2 + cv2);           // s11+s22
      const float num = (2.f * mu12 + 1e-4f) * (2.f * (s12 - mu12) + 9e-4f);
      const float den = (musq + 1e-4f) * (ssq - musq + 9e-4f);
      lsum += num * __builtin_amdgcn_rcpf(den);
    }
  }

  // ---- Block reduce, one f64 atomic per block into per-channel bucket,
  // then last-block-done ticket replaces the separate ssim_fin launch.
#pragma unroll
  for (int off = 32; off > 0; off >>= 1) lsum += __shfl_down(lsum, off, 64);
  if ((tid & 63) == 0) wsum[tid >> 6] = lsum;
  __syncthreads();
  if (tid == 0) {
    const float bsum = wsum[0] + wsum[1] + wsum[2] + wsum[3];
    unsafeAtomicAdd(&ws[nc], (double)bsum);
    __threadfence();  // release: my channel-add visible before my ticket
    unsigned* cnt = (unsigned*)(ws + NCHAN);
    const unsigned old = __hip_atomic_fetch_add(cnt, 1u, __ATOMIC_ACQ_REL,
                                                __HIP_MEMORY_SCOPE_AGENT);
    if (old == NBLK - 1) {
      // All 6143 other blocks released their adds before their tickets;
      // ACQ on the final ticket orders these agent-scope loads after them.
      double s = 0.0;
      for (int i = 0; i < NCHAN; ++i)
        s += __hip_atomic_load(&ws[i], __ATOMIC_RELAXED,
                               __HIP_MEMORY_SCOPE_AGENT);
      out[0] = (float)(1.0 - s / (double)((size_t)IMG * IMG * NCHAN));
    }
  }
}

extern "C" void kernel_launch(void* const* d_in, const int* in_sizes, int n_in,
                              void* d_out, int out_size, void* d_ws,
                              size_t ws_size, hipStream_t stream) {
  const float* pred = (const float*)d_in[0];
  const float* tgt = (const float*)d_in[1];
  double* ws = (double*)d_ws;

  // 48 channel doubles + 1 ticket counter (graph-capture-safe async op)
  hipMemsetAsync(d_ws, 0, NCHAN * sizeof(double) + sizeof(unsigned), stream);
  dim3 grid(IMG / TW, IMG / TH, NCHAN);
  ssim_main<<<grid, 256, 0, stream>>>(pred, tgt, ws, (float*)d_out);
}

// Round 8
// 170.962 us; speedup vs baseline: 3.3747x; 3.3747x over previous
//
#include <hip/hip_runtime.h>

// SSIM loss: pred/target [16,3,512,512] fp32, 11x11 gaussian (sigma=1.5),
// zero-padded SAME depthwise conv, output scalar 1 - mean(ssim_map).
//
// v13: single-basic-block forced pipeline. v11's sched_barrier failed
// because `if (hasC) hload` split phase B into multiple BBs: MachineSink
// (runs BEFORE the scheduler) sank loads across BB boundaries, and sunk
// instructions have no defined side of the barrier. Here phase B's fast
// path is ONE branchless BB: the 176 threads without a real 3rd item
// load item 591 redundantly (same 320B -> L2 broadcast, ~0 extra HBM)
// and write their hsums to dump row hs[74] via cndmask (avoids 177-way
// same-address LDS write conflict). 30 loads -> sched_barrier(0) (a
// scheduling-REGION boundary that instructions cannot cross) -> 3
// computes. RA must then hold ~120 VGPR of load buffers: VGPR count
// 140-200 is the success signal. launch_bounds(256,2) gives the budget
// (v8: never cap below the working set).
// v12 lessons: per-block threadfence = XCD L2-writeback storm (7x);
// the ~85us bench-vs-dispatch gap is fixed harness overhead, NOT
// per-node launch cost -> separate trivial ssim_fin restored.
// Keeps v7 geometry (TW=32, TH=64), packed-fp32 math, u/v reduction.

#define IMG 512
#define NCHAN 48
#define TW 32
#define TH 64
#define HR (TH + 10)   // 74 hsum rows per tile
#define PST 33         // padded plane row stride (float4s)

typedef float v2f __attribute__((ext_vector_type(2)));
typedef float v4f __attribute__((ext_vector_type(4)));

constexpr double RW1 = 0.8007374029168082;
constexpr double RW2 = 0.4111122905071876;
constexpr double RW3 = 0.1353352832366127;
constexpr double RW4 = 0.0285655007845504;
constexpr double RW5 = 0.0038659201394728;
constexpr double RSUM = 1.0 + 2.0 * (RW1 + RW2 + RW3 + RW4 + RW5);
constexpr float GW[11] = {
    (float)(RW5 / RSUM), (float)(RW4 / RSUM), (float)(RW3 / RSUM),
    (float)(RW2 / RSUM), (float)(RW1 / RSUM), (float)(1.0 / RSUM),
    (float)(RW1 / RSUM), (float)(RW2 / RSUM), (float)(RW3 / RSUM),
    (float)(RW4 / RSUM), (float)(RW5 / RSUM)};

// ---- VOP3P packed fp32 (gfx90a+; hipcc never auto-emits these).
// Register-only asm: no memory ops, no waitcnt interaction.
__device__ __forceinline__ v2f pk_fma(v2f a, v2f b, v2f c) {
  v2f d;
  asm("v_pk_fma_f32 %0, %1, %2, %3" : "=v"(d) : "v"(a), "v"(b), "v"(c));
  return d;
}
__device__ __forceinline__ v2f pk_mul(v2f a, v2f b) {
  v2f d;
  asm("v_pk_mul_f32 %0, %1, %2" : "=v"(d) : "v"(a), "v"(b));
  return d;
}

// ---- Phase B building blocks: item j in [0, HR*8) = 4 hsum outputs.
template <bool CHECKED>
__device__ __forceinline__ void hload(const float* __restrict__ P,
                                      const float* __restrict__ T, int r0t,
                                      int c0, int j, v4f* vp, v4f* vt) {
  const int g = j & 7;
  const int h = j >> 3;
  const int gy = r0t - 5 + h;
  const int gx0 = c0 + g * 4 - 8;  // aligned 20-float window (mult of 4)
  if (CHECKED) {
    const bool rowok = (gy >= 0) && (gy < IMG);
    const float* __restrict__ Prow = P + (size_t)gy * IMG;
    const float* __restrict__ Trow = T + (size_t)gy * IMG;
#pragma unroll
    for (int q = 0; q < 5; ++q) {
      const int gx = gx0 + q * 4;
      vp[q] = (v4f){0.f, 0.f, 0.f, 0.f};
      vt[q] = vp[q];
      // gx is a multiple of 4 and IMG%4==0: float4 is all-in or all-out.
      if (rowok && gx >= 0 && gx < IMG) {
        vp[q] = *(const v4f*)(Prow + gx);
        vt[q] = *(const v4f*)(Trow + gx);
      }
    }
  } else {
    const float* __restrict__ Prow = P + (size_t)gy * IMG + gx0;
    const float* __restrict__ Trow = T + (size_t)gy * IMG + gx0;
#pragma unroll
    for (int q = 0; q < 5; ++q) {
      vp[q] = *(const v4f*)(Prow + q * 4);
      vt[q] = *(const v4f*)(Trow + q * 4);
    }
  }
}

// Compute 4 hsum outputs from a loaded 20-float window; write to
// explicit (h_w, g_w) so dummy items can be routed to the dump row.
__device__ __forceinline__ void hcompute_to(const v4f* vp, const v4f* vt,
                                            int h_w, int g_w,
                                            float4 (*hs)[PST]) {
  v2f uv[20], sq[20];
#pragma unroll
  for (int q = 0; q < 5; ++q) {
    const v4f p4 = vp[q], t4 = vt[q];
    uv[q * 4 + 0] = (v2f){p4.x + t4.x, p4.x - t4.x};
    uv[q * 4 + 1] = (v2f){p4.y + t4.y, p4.y - t4.y};
    uv[q * 4 + 2] = (v2f){p4.z + t4.z, p4.z - t4.z};
    uv[q * 4 + 3] = (v2f){p4.w + t4.w, p4.w - t4.w};
  }
#pragma unroll
  for (int i = 3; i <= 16; ++i) sq[i] = pk_mul(uv[i], uv[i]);
#pragma unroll
  for (int o = 0; o < 4; ++o) {
    v2f amu = (v2f){0.f, 0.f};  // (cu, cv)
    v2f asq = (v2f){0.f, 0.f};  // (cu2, cv2)
#pragma unroll
    for (int k = 0; k < 11; ++k) {
      const v2f w = (v2f){GW[k], GW[k]};
      amu = pk_fma(uv[3 + o + k], w, amu);
      asq = pk_fma(sq[3 + o + k], w, asq);
    }
    hs[h_w][g_w * 4 + o] = make_float4(amu.x, amu.y, asq.x, asq.y);
  }
}

// ---- interior: single-BB forced pipeline.
__device__ __forceinline__ void phase_b_fast(const float* __restrict__ P,
                                             const float* __restrict__ T,
                                             int r0t, int c0, int tid,
                                             float4 (*hs)[PST]) {
  v4f ap[5], at[5], bp[5], bt[5], cp[5], ct[5];
  const bool real = tid < (HR * 8 - 512);        // 80 real 3rd items
  const int jC = real ? tid + 512 : (HR * 8 - 1);  // dummies read item 591
  const int hC = real ? (jC >> 3) : HR;            // dummies write row 74
  hload<false>(P, T, r0t, c0, tid, ap, at);
  hload<false>(P, T, r0t, c0, tid + 256, bp, bt);
  hload<false>(P, T, r0t, c0, jC, cp, ct);
  // Region boundary: the 30 b128 loads above cannot be scheduled below,
  // compute cannot be scheduled above. RA must hold all destinations.
  __builtin_amdgcn_sched_barrier(0);
  hcompute_to(ap, at, tid >> 3, tid & 7, hs);
  hcompute_to(bp, bt, (tid + 256) >> 3, (tid + 256) & 7, hs);
  hcompute_to(cp, ct, hC, tid & 7, hs);
}

// ---- boundary: compiler-scheduled checked path (34% of blocks)
__device__ __forceinline__ void phase_b_chk(const float* __restrict__ P,
                                            const float* __restrict__ T,
                                            int r0t, int c0, int tid,
                                            float4 (*hs)[PST]) {
  v4f ap[5], at[5], bp[5], bt[5];
  hload<true>(P, T, r0t, c0, tid, ap, at);
  hload<true>(P, T, r0t, c0, tid + 256, bp, bt);
  hcompute_to(ap, at, tid >> 3, tid & 7, hs);
  hcompute_to(bp, bt, (tid + 256) >> 3, (tid + 256) & 7, hs);
  if (tid < HR * 8 - 512) {
    hload<true>(P, T, r0t, c0, tid + 512, ap, at);
    hcompute_to(ap, at, (tid + 512) >> 3, (tid + 512) & 7, hs);
  }
}

__global__ __launch_bounds__(256, 2) void ssim_main(
    const float* __restrict__ pred, const float* __restrict__ tgt,
    double* __restrict__ ws) {
  __shared__ float4 hs[HR + 1][PST];  // (cu,cv,cu2,cv2); row HR = dump row
  __shared__ float wsum[4];

  const int tid = threadIdx.x;
  const int c0 = blockIdx.x * TW;
  const int r0t = blockIdx.y * TH;
  const int nc = blockIdx.z;
  const size_t base = (size_t)nc * IMG * IMG;
  const float* __restrict__ P = pred + base;
  const float* __restrict__ T = tgt + base;

  const bool interior =
      (c0 != 0) && (c0 != IMG - TW) && (r0t != 0) && (r0t != IMG - TH);
  if (interior)
    phase_b_fast(P, T, r0t, c0, tid, hs);
  else
    phase_b_chk(P, T, r0t, c0, tid, hs);
  __syncthreads();

  // ---- Phase C: vertical windowed sums, row-streaming, 8 outputs/thread
  float lsum = 0.f;
  {
    const int x = tid & (TW - 1);
    const int r0 = (tid >> 5) * 8;  // 8 strips * 8 rows = 64
    v2f amu[8], asq[8];
#pragma unroll
    for (int o = 0; o < 8; ++o) {
      amu[o] = (v2f){0.f, 0.f};
      asq[o] = (v2f){0.f, 0.f};
    }
#pragma unroll
    for (int j = 0; j < 18; ++j) {
      const float4 h4 = hs[r0 + j][x];
      const v2f hmu = (v2f){h4.x, h4.y};
      const v2f hsq = (v2f){h4.z, h4.w};
#pragma unroll
      for (int o = 0; o < 8; ++o) {
        const int k = j - o;
        if (k >= 0 && k < 11) {
          const v2f w = (v2f){GW[k], GW[k]};
          amu[o] = pk_fma(hmu, w, amu[o]);
          asq[o] = pk_fma(hsq, w, asq[o]);
        }
      }
    }
#pragma unroll
    for (int o = 0; o < 8; ++o) {
      const v2f m2 = pk_mul(amu[o], amu[o]);   // (cu^2, cv^2)
      const float cusq = m2.x, cvsq = m2.y;
      const float cu2 = asq[o].x, cv2 = asq[o].y;
      const float mu12 = 0.25f * (cusq - cvsq);       // mu1*mu2
      const float musq = 0.5f * (cusq + cvsq);        // mu1^2+mu2^2
      const float s12 = 0.25f * (cu2 - cv2);          // conv(p*t)
      const float ssq = 0.5f * (cu2 + cv2);           // s11+s22
      const float num = (2.f * mu12 + 1e-4f) * (2.f * (s12 - mu12) + 9e-4f);
      const float den = (musq + 1e-4f) * (ssq - musq + 9e-4f);
      lsum += num * __builtin_amdgcn_rcpf(den);
    }
  }

  // ---- Block reduce, one f64 atomic per block into per-channel bucket
#pragma unroll
  for (int off = 32; off > 0; off >>= 1) lsum += __shfl_down(lsum, off, 64);
  if ((tid & 63) == 0) wsum[tid >> 6] = lsum;
  __syncthreads();
  if (tid == 0) {
    const float bsum = wsum[0] + wsum[1] + wsum[2] + wsum[3];
    unsafeAtomicAdd(&ws[nc], (double)bsum);
  }
}

__global__ void ssim_fin(const double* __restrict__ ws,
                         float* __restrict__ out) {
  const int l = threadIdx.x;
  double v = (l < NCHAN) ? ws[l] : 0.0;
#pragma unroll
  for (int off = 32; off > 0; off >>= 1) v += __shfl_down(v, off, 64);
  if (l == 0) out[0] = (float)(1.0 - v / (double)(IMG * IMG * NCHAN));
}

extern "C" void kernel_launch(void* const* d_in, const int* in_sizes, int n_in,
                              void* d_out, int out_size, void* d_ws,
                              size_t ws_size, hipStream_t stream) {
  const float* pred = (const float*)d_in[0];
  const float* tgt = (const float*)d_in[1];
  double* ws = (double*)d_ws;

  hipMemsetAsync(d_ws, 0, NCHAN * sizeof(double), stream);
  dim3 grid(IMG / TW, IMG / TH, NCHAN);
  ssim_main<<<grid, 256, 0, stream>>>(pred, tgt, ws);
  ssim_fin<<<1, 64, 0, stream>>>(ws, (float*)d_out);
}

// Round 9
// 166.947 us; speedup vs baseline: 3.4559x; 1.0240x over previous
//
#include <hip/hip_runtime.h>

// SSIM loss: pred/target [16,3,512,512] fp32, 11x11 gaussian (sigma=1.5),
// zero-padded SAME depthwise conv, output scalar 1 - mean(ssim_map).
//
// v14: global_load_lds staging. v10/v10b/v11/v13 proved hipcc will not
// hold register load-batches (VGPR never rose above 72); DMA staging
// sidesteps registers entirely: 74 global_load_lds instructions per
// block (24 active lanes x 16B = one row of P+T each) stream the raw
// tile into LDS fire-and-forget; ONE __syncthreads (drains vmcnt) and
// all subsequent compute is LDS-local ds_read_b128 + packed-fp32 math.
// LDS layout: [74 rows][33 float4] = 39.1 KB (same as v7 -> 4 blocks/CU).
//   raw row:  slots 0..11 = P (12 f4 = 48 floats), 12..23 = T, rest pad.
//   hs row:   OVERLAYS raw after consumption: slots 0..31 = (cu,cv,cu2,cv2).
// Overlay needs no extra barrier: item rows are wave-private (item A of
// wave w covers rows 8w..8w+7; B: 32+8w..; C: 64+8w..) and a wave's DS
// ops execute in FIFO order (reads of a row precede that item's writes).
// Stride 33 keeps all four LDS access patterns bank-uniform (33 = 1 mod 8).
// Boundary blocks (34%) keep v7's checked register path, writing the
// same overlay. Math identical to v7 -> absmax 0.

#define IMG 512
#define NCHAN 48
#define TW 32
#define TH 64
#define HR (TH + 10)   // 74 rows (tile + vertical halo)
#define RST 33         // LDS row stride in float4s

typedef float v2f __attribute__((ext_vector_type(2)));
typedef float v4f __attribute__((ext_vector_type(4)));

constexpr double RW1 = 0.8007374029168082;
constexpr double RW2 = 0.4111122905071876;
constexpr double RW3 = 0.1353352832366127;
constexpr double RW4 = 0.0285655007845504;
constexpr double RW5 = 0.0038659201394728;
constexpr double RSUM = 1.0 + 2.0 * (RW1 + RW2 + RW3 + RW4 + RW5);
constexpr float GW[11] = {
    (float)(RW5 / RSUM), (float)(RW4 / RSUM), (float)(RW3 / RSUM),
    (float)(RW2 / RSUM), (float)(RW1 / RSUM), (float)(1.0 / RSUM),
    (float)(RW1 / RSUM), (float)(RW2 / RSUM), (float)(RW3 / RSUM),
    (float)(RW4 / RSUM), (float)(RW5 / RSUM)};

// ---- VOP3P packed fp32 (gfx90a+; hipcc never auto-emits these).
// Register-only asm: no memory ops, no waitcnt interaction.
__device__ __forceinline__ v2f pk_fma(v2f a, v2f b, v2f c) {
  v2f d;
  asm("v_pk_fma_f32 %0, %1, %2, %3" : "=v"(d) : "v"(a), "v"(b), "v"(c));
  return d;
}
__device__ __forceinline__ v2f pk_mul(v2f a, v2f b) {
  v2f d;
  asm("v_pk_mul_f32 %0, %1, %2" : "=v"(d) : "v"(a), "v"(b));
  return d;
}

// ---- async global->LDS DMA, 16B per active lane; lane l writes
// lds_base + l*16 (wave-uniform base). Size must be a literal.
__device__ __forceinline__ void gload_lds16(const float* g, float4* l) {
  __builtin_amdgcn_global_load_lds(
      (const __attribute__((address_space(1))) void*)g,
      (__attribute__((address_space(3))) void*)l, 16, 0, 0);
}

// ---- shared compute core: 20-float windows (5 f4 per array) -> 4 hs
// outputs written at dst[0..3] (= &lds4[h*RST + 4*g]).
__device__ __forceinline__ void hcompute_w(const v4f* vp, const v4f* vt,
                                           float4* dst) {
  v2f uv[20], sq[20];
#pragma unroll
  for (int q = 0; q < 5; ++q) {
    const v4f p4 = vp[q], t4 = vt[q];
    uv[q * 4 + 0] = (v2f){p4.x + t4.x, p4.x - t4.x};
    uv[q * 4 + 1] = (v2f){p4.y + t4.y, p4.y - t4.y};
    uv[q * 4 + 2] = (v2f){p4.z + t4.z, p4.z - t4.z};
    uv[q * 4 + 3] = (v2f){p4.w + t4.w, p4.w - t4.w};
  }
#pragma unroll
  for (int i = 3; i <= 16; ++i) sq[i] = pk_mul(uv[i], uv[i]);
#pragma unroll
  for (int o = 0; o < 4; ++o) {
    v2f amu = (v2f){0.f, 0.f};  // (cu, cv)
    v2f asq = (v2f){0.f, 0.f};  // (cu2, cv2)
#pragma unroll
    for (int k = 0; k < 11; ++k) {
      const v2f w = (v2f){GW[k], GW[k]};
      amu = pk_fma(uv[3 + o + k], w, amu);
      asq = pk_fma(sq[3 + o + k], w, asq);
    }
    dst[o] = make_float4(amu.x, amu.y, asq.x, asq.y);
  }
}

// ---- interior item: read windows from staged LDS raw, write overlay.
__device__ __forceinline__ void item_fast(int j, float4* lds4) {
  const int g = j & 7;
  const int h = j >> 3;
  float4* row = lds4 + h * RST;
  v4f p4[5], t4[5];
#pragma unroll
  for (int q = 0; q < 5; ++q) {
    p4[q] = *(const v4f*)(row + g + q);       // ds_read_b128
    t4[q] = *(const v4f*)(row + 12 + g + q);
  }
  hcompute_w(p4, t4, row + 4 * g);
}

// ---- boundary item: v7 checked global->register path, same overlay.
__device__ __forceinline__ void item_chk(const float* __restrict__ P,
                                         const float* __restrict__ T, int r0t,
                                         int c0, int j, float4* lds4) {
  const int g = j & 7;
  const int h = j >> 3;
  const int gy = r0t - 5 + h;
  const int gx0 = c0 + g * 4 - 8;  // aligned 20-float window (mult of 4)
  const bool rowok = (gy >= 0) && (gy < IMG);
  const float* __restrict__ Prow = P + (size_t)gy * IMG;
  const float* __restrict__ Trow = T + (size_t)gy * IMG;
  v4f p4[5], t4[5];
#pragma unroll
  for (int q = 0; q < 5; ++q) {
    const int gx = gx0 + q * 4;
    p4[q] = (v4f){0.f, 0.f, 0.f, 0.f};
    t4[q] = p4[q];
    // gx is a multiple of 4 and IMG%4==0: float4 is all-in or all-out.
    if (rowok && gx >= 0 && gx < IMG) {
      p4[q] = *(const v4f*)(Prow + gx);
      t4[q] = *(const v4f*)(Trow + gx);
    }
  }
  hcompute_w(p4, t4, lds4 + h * RST + 4 * g);
}

__global__ __launch_bounds__(256, 4) void ssim_main(
    const float* __restrict__ pred, const float* __restrict__ tgt,
    double* __restrict__ ws) {
  __shared__ float4 lds4[HR * RST];  // raw pixels, then hs overlay
  __shared__ float wsum[4];

  const int tid = threadIdx.x;
  const int c0 = blockIdx.x * TW;
  const int r0t = blockIdx.y * TH;
  const int nc = blockIdx.z;
  const size_t base = (size_t)nc * IMG * IMG;
  const float* __restrict__ P = pred + base;
  const float* __restrict__ T = tgt + base;

  const bool interior =
      (c0 != 0) && (c0 != IMG - TW) && (r0t != 0) && (r0t != IMG - TH);

  if (interior) {
    // ---- Phase A: DMA-stage the raw tile. One instruction per row:
    // lanes 0..11 stage P f4s 0..11, lanes 12..23 stage T f4s 12..23.
    const int lane = tid & 63;
    const int wv = tid >> 6;
    const int q = (lane < 12) ? lane : lane - 12;
    const float* arr = (lane < 12) ? P : T;
    const float* srcbase = arr + (size_t)(r0t - 5) * IMG + (c0 - 8) + q * 4;
    for (int r = wv; r < HR; r += 4) {
      if (lane < 24) gload_lds16(srcbase + (size_t)r * IMG, lds4 + r * RST);
    }
    __syncthreads();  // drains vmcnt (DMA landed) + all waves see raw
    // ---- Phase B: 592 items from LDS; rows are wave-private, DS FIFO
    // orders each item's reads before its overlay writes.
    item_fast(tid, lds4);
    item_fast(tid + 256, lds4);
    if (tid < HR * 8 - 512) item_fast(tid + 512, lds4);
  } else {
    item_chk(P, T, r0t, c0, tid, lds4);
    item_chk(P, T, r0t, c0, tid + 256, lds4);
    if (tid < HR * 8 - 512) item_chk(P, T, r0t, c0, tid + 512, lds4);
  }
  __syncthreads();

  // ---- Phase C: vertical windowed sums, row-streaming, 8 outputs/thread
  float lsum = 0.f;
  {
    const int x = tid & (TW - 1);
    const int r0 = (tid >> 5) * 8;  // 8 strips * 8 rows = 64
    v2f amu[8], asq[8];
#pragma unroll
    for (int o = 0; o < 8; ++o) {
      amu[o] = (v2f){0.f, 0.f};
      asq[o] = (v2f){0.f, 0.f};
    }
#pragma unroll
    for (int j = 0; j < 18; ++j) {
      const float4 h4 = lds4[(r0 + j) * RST + x];
      const v2f hmu = (v2f){h4.x, h4.y};
      const v2f hsq = (v2f){h4.z, h4.w};
#pragma unroll
      for (int o = 0; o < 8; ++o) {
        const int k = j - o;
        if (k >= 0 && k < 11) {
          const v2f w = (v2f){GW[k], GW[k]};
          amu[o] = pk_fma(hmu, w, amu[o]);
          asq[o] = pk_fma(hsq, w, asq[o]);
        }
      }
    }
#pragma unroll
    for (int o = 0; o < 8; ++o) {
      const v2f m2 = pk_mul(amu[o], amu[o]);   // (cu^2, cv^2)
      const float cusq = m2.x, cvsq = m2.y;
      const float cu2 = asq[o].x, cv2 = asq[o].y;
      const float mu12 = 0.25f * (cusq - cvsq);       // mu1*mu2
      const float musq = 0.5f * (cusq + cvsq);        // mu1^2+mu2^2
      const float s12 = 0.25f * (cu2 - cv2);          // conv(p*t)
      const float ssq = 0.5f * (cu2 + cv2);           // s11+s22
      const float num = (2.f * mu12 + 1e-4f) * (2.f * (s12 - mu12) + 9e-4f);
      const float den = (musq + 1e-4f) * (ssq - musq + 9e-4f);
      lsum += num * __builtin_amdgcn_rcpf(den);
    }
  }

  // ---- Block reduce, one f64 atomic per block into per-channel bucket
#pragma unroll
  for (int off = 32; off > 0; off >>= 1) lsum += __shfl_down(lsum, off, 64);
  if ((tid & 63) == 0) wsum[tid >> 6] = lsum;
  __syncthreads();
  if (tid == 0) {
    const float bsum = wsum[0] + wsum[1] + wsum[2] + wsum[3];
    unsafeAtomicAdd(&ws[nc], (double)bsum);
  }
}

__global__ void ssim_fin(const double* __restrict__ ws,
                         float* __restrict__ out) {
  const int l = threadIdx.x;
  double v = (l < NCHAN) ? ws[l] : 0.0;
#pragma unroll
  for (int off = 32; off > 0; off >>= 1) v += __shfl_down(v, off, 64);
  if (l == 0) out[0] = (float)(1.0 - v / (double)(IMG * IMG * NCHAN));
}

extern "C" void kernel_launch(void* const* d_in, const int* in_sizes, int n_in,
                              void* d_out, int out_size, void* d_ws,
                              size_t ws_size, hipStream_t stream) {
  const float* pred = (const float*)d_in[0];
  const float* tgt = (const float*)d_in[1];
  double* ws = (double*)d_ws;

  hipMemsetAsync(d_ws, 0, NCHAN * sizeof(double), stream);
  dim3 grid(IMG / TW, IMG / TH, NCHAN);
  ssim_main<<<grid, 256, 0, stream>>>(pred, tgt, ws);
  ssim_fin<<<1, 64, 0, stream>>>(ws, (float*)d_out);
}